// Round 7
// baseline (266.951 us; speedup 1.0000x reference)
//
#include <hip/hip_runtime.h>

// BoundaryKDV13: per-pixel channel-softmax KL(T||S), masked by class-boundary
// pixels, binned per (batch, class 1..13), normalized, summed to scalar.
//
// V13 vs V11/V12: hand-written 2-deep software pipeline over channels.
// Evidence: V11/V12 deliver 243 MB / ~96us = 2.5 TB/s = 4 B/cyc/CU (copy
// achieves 10), VALUBusy 10%, no spill -- consistent with the compiler's
// rolled-loop shape (loads at top, vmcnt(0), compute) never issuing
// iteration c+1's loads before the wait on c's data. unroll hints don't
// fix it (V12: VGPR 28, loads re-serialized). So: named prefetch buffers
// 2 channels ahead, #pragma unroll 1 to forbid flattening, uniform guard
// branch whose BB boundary pins the prefetch loads above the compute.
// Steady-state auto-wait becomes vmcnt(4): 4 KB/wave always in flight,
// ~128 KB/CU at full residency. Live set ~46 VGPR: no spill.
// Prefetch guarded (b=7, c+2>=14 would read past the S/T allocation).
//
// Shapes: preds_S/preds_T [8,14,512,512] f32, gt [8,1,512,512] i32, out: 1 f32.

#define CC 14
#define KB 13          // boundary classes 1..13
#define BB 8
#define HH 512
#define WW 512
#define PP (HH * WW)   // 262144 pixels per image
#define PIX_PER_BLOCK 1024
#define BLOCKS_PER_IMG (PP / PIX_PER_BLOCK)   // 256

// ws layout (floats): [0 .. 103] kl_sum[b][k-1], [104 .. 207] n[b][k-1]
#define NBINS (BB * KB)

__global__ void zero_ws_kernel(float* __restrict__ ws) {
    int i = threadIdx.x;
    if (i < 2 * NBINS) ws[i] = 0.0f;
}

__global__ __launch_bounds__(256) void boundary_kl_kernel(
        const float* __restrict__ S, const float* __restrict__ T,
        const int* __restrict__ gt, float* __restrict__ ws) {
    const int tid = threadIdx.x;
    const int b   = blockIdx.x / BLOCKS_PER_IMG;
    const int p0  = (blockIdx.x % BLOCKS_PER_IMG) * PIX_PER_BLOCK + tid * 4;

    __shared__ float s_kl[KB + 1];
    __shared__ float s_n[KB + 1];
    if (tid <= KB) { s_kl[tid] = 0.0f; s_n[tid] = 0.0f; }
    __syncthreads();

    const float* Sb = S + (size_t)b * CC * PP + p0;
    const float* Tb = T + (size_t)b * CC * PP + p0;
    const int*  gtb = gt + (size_t)b * PP;

    // ---- prologue: fill the 2-deep pipeline ----
    float4 xs_c = *(const float4*)(Sb);
    float4 xt_c = *(const float4*)(Tb);
    float4 xs_n = *(const float4*)(Sb + PP);
    float4 xt_n = *(const float4*)(Tb + PP);

    // ---- single-pass softmax-KL accumulation (no max subtraction) ----
    // kl_pix = sum_c pT*(log pT - log pS)
    //        = [sum_c e^{xt}*(xt - xs)] / zT + log zS - log zT
    float4 zS = make_float4(0.f, 0.f, 0.f, 0.f);
    float4 zT = make_float4(0.f, 0.f, 0.f, 0.f);
    float4 A  = make_float4(0.f, 0.f, 0.f, 0.f);
#pragma unroll 1
    for (int c = 0; c < CC; ++c) {
        // prefetch channel c+2 (issued BEFORE the wait on channel c's data;
        // the uniform branch's BB boundary keeps these loads above the compute)
        float4 xs_p = make_float4(0.f, 0.f, 0.f, 0.f);
        float4 xt_p = make_float4(0.f, 0.f, 0.f, 0.f);
        if (c + 2 < CC) {
            xs_p = *(const float4*)(Sb + (size_t)(c + 2) * PP);
            xt_p = *(const float4*)(Tb + (size_t)(c + 2) * PP);
        }

        const float4 eS = make_float4(__expf(xs_c.x), __expf(xs_c.y), __expf(xs_c.z), __expf(xs_c.w));
        const float4 eT = make_float4(__expf(xt_c.x), __expf(xt_c.y), __expf(xt_c.z), __expf(xt_c.w));
        zS.x += eS.x; zS.y += eS.y; zS.z += eS.z; zS.w += eS.w;
        zT.x += eT.x; zT.y += eT.y; zT.z += eT.z; zT.w += eT.w;
        A.x = fmaf(eT.x, xt_c.x - xs_c.x, A.x);
        A.y = fmaf(eT.y, xt_c.y - xs_c.y, A.y);
        A.z = fmaf(eT.z, xt_c.z - xs_c.z, A.z);
        A.w = fmaf(eT.w, xt_c.w - xs_c.w, A.w);

        // rotate pipeline
        xs_c = xs_n; xt_c = xt_n;
        xs_n = xs_p; xt_n = xt_p;
    }

    float kl[4];
    kl[0] = __fdividef(A.x, zT.x) + __logf(zS.x) - __logf(zT.x);
    kl[1] = __fdividef(A.y, zT.y) + __logf(zS.y) - __logf(zT.y);
    kl[2] = __fdividef(A.z, zT.z) + __logf(zS.z) - __logf(zT.z);
    kl[3] = __fdividef(A.w, zT.w) + __logf(zS.w) - __logf(zT.w);

    // ---- boundary test (cross erosion, zero border => border pixels are boundary) ----
    const int h = p0 >> 9;        // p0 / 512
    const int w = p0 & (WW - 1);  // p0 % 512 (multiple of 4)
    int4 g = *(const int4*)(gtb + p0);
    int4 gu = make_int4(-1, -1, -1, -1);
    int4 gd = make_int4(-1, -1, -1, -1);
    if (h > 0)      gu = *(const int4*)(gtb + p0 - WW);
    if (h < HH - 1) gd = *(const int4*)(gtb + p0 + WW);
    const int gl = (w > 0)       ? gtb[p0 - 1] : -1;
    const int gr = (w + 4 < WW)  ? gtb[p0 + 4] : -1;

    const int gc[4]  = {g.x, g.y, g.z, g.w};
    const int gup[4] = {gu.x, gu.y, gu.z, gu.w};
    const int gdn[4] = {gd.x, gd.y, gd.z, gd.w};
    const int glf[4] = {gl, g.x, g.y, g.z};
    const int grt[4] = {g.y, g.z, g.w, gr};

#pragma unroll
    for (int j = 0; j < 4; ++j) {
        const int k = gc[j];
        const bool eroded = (glf[j] == k) & (grt[j] == k) & (gup[j] == k) & (gdn[j] == k);
        if (k >= 1 && !eroded) {
            atomicAdd(&s_kl[k], kl[j]);
            atomicAdd(&s_n[k], 1.0f);
        }
    }
    __syncthreads();

    if (tid >= 1 && tid <= KB) {
        atomicAdd(&ws[b * KB + (tid - 1)], s_kl[tid]);
        atomicAdd(&ws[NBINS + b * KB + (tid - 1)], s_n[tid]);
    }
}

__global__ void finalize_kernel(const float* __restrict__ ws,
                                const int* __restrict__ gt,
                                float* __restrict__ out) {
    __shared__ float partial[128];
    const int tid = threadIdx.x;  // 128 threads
    float t = 0.0f;
    if (tid < NBINS) {
        const int b = tid / KB;
        const int k = (tid % KB) + 1;
        const float kl = ws[tid];
        const float n  = ws[NBINS + tid];
        // Pixel p=0 of image b is a corner -> boundary iff gt[b,0,0] >= 1.
        // valid = exists boundary pixel with flat index > 0.
        const int k0 = gt[(size_t)b * PP];
        const float sub = (k0 == k) ? 1.0f : 0.0f;   // k >= 1 always here
        const float npos = n - sub;
        t = (npos > 0.0f) ? (kl / ((float)CC * fmaxf(n, 1.0f))) : 0.0f;
    }
    partial[tid] = t;
    __syncthreads();
    for (int s = 64; s > 0; s >>= 1) {
        if (tid < s) partial[tid] += partial[tid + s];
        __syncthreads();
    }
    if (tid == 0) out[0] = partial[0];  // LOSS_WEIGHT * TAU^2 = 1
}

extern "C" void kernel_launch(void* const* d_in, const int* in_sizes, int n_in,
                              void* d_out, int out_size, void* d_ws, size_t ws_size,
                              hipStream_t stream) {
    const float* S  = (const float*)d_in[0];
    const float* T  = (const float*)d_in[1];
    const int*   gt = (const int*)d_in[2];
    float* out = (float*)d_out;
    float* ws  = (float*)d_ws;

    hipLaunchKernelGGL(zero_ws_kernel, dim3(1), dim3(256), 0, stream, ws);
    hipLaunchKernelGGL(boundary_kl_kernel, dim3(BB * BLOCKS_PER_IMG), dim3(256), 0, stream,
                       S, T, gt, ws);
    hipLaunchKernelGGL(finalize_kernel, dim3(1), dim3(128), 0, stream, ws, gt, out);
}

// Round 8
// 257.914 us; speedup vs baseline: 1.0350x; 1.0350x over previous
//
#include <hip/hip_runtime.h>

// BoundaryKDV14: per-pixel channel-softmax KL(T||S), masked by class-boundary
// pixels, binned per (batch, class 1..13), normalized, summed to scalar.
//
// V14: counted-vmcnt DMA pipeline via global_load_lds. Evidence trail:
// V7/V11/V12/V13 (3-pass, rolled, unroll-4, register SW-pipeline) ALL
// deliver ~2.5 TB/s (243 MB / ~96-103us); the allocator converges to
// <=32 VGPR and emits load-pair -> vmcnt(0) -> compute regardless of
// source shape (~2 KB/wave in flight). Fix: stage to wave-private LDS
// ring buffers with __builtin_amdgcn_global_load_lds (width 16, zero
// payload VGPRs), hand-coded literal s_waitcnt vmcnt(6/4/2/0) -- never
// draining in steady state. 4-buffer ring, 3 stages ahead = 6-8 KB/wave
// in flight (~140 KB/CU at 20 waves). No barriers: buffers are
// wave-private; program order + compiler lgkmcnt covers LDS reuse.
// LDS 32 KB/block -> 5 blocks/CU (same effective occupancy as V11-13).
//
// Shapes: preds_S/preds_T [8,14,512,512] f32, gt [8,1,512,512] i32, out: 1 f32.

#define CC 14
#define KB 13          // boundary classes 1..13
#define BB 8
#define HH 512
#define WW 512
#define PP (HH * WW)   // 262144 pixels per image
#define PIX_PER_BLOCK 1024
#define BLOCKS_PER_IMG (PP / PIX_PER_BLOCK)   // 256

// ws layout (floats): [0 .. 103] kl_sum[b][k-1], [104 .. 207] n[b][k-1]
#define NBINS (BB * KB)

__global__ void zero_ws_kernel(float* __restrict__ ws) {
    int i = threadIdx.x;
    if (i < 2 * NBINS) ws[i] = 0.0f;
}

__device__ __forceinline__ void stage16(const float* g, const float* l) {
    __builtin_amdgcn_global_load_lds(
        (const __attribute__((address_space(1))) void*)g,
        (__attribute__((address_space(3))) void*)l,
        16, 0, 0);
}

__global__ __launch_bounds__(256) void boundary_kl_kernel(
        const float* __restrict__ S, const float* __restrict__ T,
        const int* __restrict__ gt, float* __restrict__ ws) {
    const int tid = threadIdx.x;
    const int b   = blockIdx.x / BLOCKS_PER_IMG;
    const int p0  = (blockIdx.x % BLOCKS_PER_IMG) * PIX_PER_BLOCK + tid * 4;

    // wave-private staging ring: 4 waves x 4 bufs x (256 S + 256 T) floats
    __shared__ float lds[4 * 4 * 512];   // 32 KB

    __shared__ float s_kl[KB + 1];
    __shared__ float s_n[KB + 1];
    if (tid <= KB) { s_kl[tid] = 0.0f; s_n[tid] = 0.0f; }
    __syncthreads();

    const float* Sb = S + (size_t)b * CC * PP + p0;   // per-lane global src
    const float* Tb = T + (size_t)b * CC * PP + p0;
    const int*  gtb = gt + (size_t)b * PP;

    const int wslot = (tid >> 6) * 2048;   // this wave's 8 KB region (floats)
    const int lofs  = (tid & 63) * 4;      // this lane's float offset in a buffer

    float4 zS = make_float4(0.f, 0.f, 0.f, 0.f);
    float4 zT = make_float4(0.f, 0.f, 0.f, 0.f);
    float4 A  = make_float4(0.f, 0.f, 0.f, 0.f);

    // STAGE(c): DMA channel c (S and T, 1 KB each per wave) into ring buf c&3.
    // LDS dest is wave-uniform base; HW adds lane*16 — matches lofs layout.
#define STAGE(c) do {                                                        \
        stage16(Sb + (size_t)(c) * PP, &lds[wslot + ((c) & 3) * 512]);       \
        stage16(Tb + (size_t)(c) * PP, &lds[wslot + ((c) & 3) * 512 + 256]); \
    } while (0)

#define CONSUME(c) do {                                                       \
        const float4 xs = *(const float4*)&lds[wslot + ((c) & 3) * 512 + lofs];       \
        const float4 xt = *(const float4*)&lds[wslot + ((c) & 3) * 512 + 256 + lofs]; \
        const float4 eS = make_float4(__expf(xs.x), __expf(xs.y), __expf(xs.z), __expf(xs.w)); \
        const float4 eT = make_float4(__expf(xt.x), __expf(xt.y), __expf(xt.z), __expf(xt.w)); \
        zS.x += eS.x; zS.y += eS.y; zS.z += eS.z; zS.w += eS.w;               \
        zT.x += eT.x; zT.y += eT.y; zT.z += eT.z; zT.w += eT.w;               \
        A.x = fmaf(eT.x, xt.x - xs.x, A.x);                                   \
        A.y = fmaf(eT.y, xt.y - xs.y, A.y);                                   \
        A.z = fmaf(eT.z, xt.z - xs.z, A.z);                                   \
        A.w = fmaf(eT.w, xt.w - xs.w, A.w);                                   \
    } while (0)

#define WAITVM(n) asm volatile("s_waitcnt vmcnt(" #n ")" ::: "memory")

    // prologue: 3 stages in flight (6 loads)
    STAGE(0); STAGE(1); STAGE(2);
    // steady state: issue stage c+3, wait for stage c (2 newer stages = 6 loads
    // outstanding allowed), consume from LDS. vmcnt never drains to 0 here.
    STAGE(3);  WAITVM(6); CONSUME(0);
    STAGE(4);  WAITVM(6); CONSUME(1);
    STAGE(5);  WAITVM(6); CONSUME(2);
    STAGE(6);  WAITVM(6); CONSUME(3);
    STAGE(7);  WAITVM(6); CONSUME(4);
    STAGE(8);  WAITVM(6); CONSUME(5);
    STAGE(9);  WAITVM(6); CONSUME(6);
    STAGE(10); WAITVM(6); CONSUME(7);
    STAGE(11); WAITVM(6); CONSUME(8);
    STAGE(12); WAITVM(6); CONSUME(9);
    STAGE(13); WAITVM(6); CONSUME(10);
    // epilogue drain: 4 -> 2 -> 0
    WAITVM(4); CONSUME(11);
    WAITVM(2); CONSUME(12);
    WAITVM(0); CONSUME(13);

#undef STAGE
#undef CONSUME
#undef WAITVM

    float kl[4];
    kl[0] = __fdividef(A.x, zT.x) + __logf(zS.x) - __logf(zT.x);
    kl[1] = __fdividef(A.y, zT.y) + __logf(zS.y) - __logf(zT.y);
    kl[2] = __fdividef(A.z, zT.z) + __logf(zS.z) - __logf(zT.z);
    kl[3] = __fdividef(A.w, zT.w) + __logf(zS.w) - __logf(zT.w);

    // ---- boundary test (cross erosion, zero border => border pixels are boundary) ----
    const int h = p0 >> 9;        // p0 / 512
    const int w = p0 & (WW - 1);  // p0 % 512 (multiple of 4)
    int4 g = *(const int4*)(gtb + p0);
    int4 gu = make_int4(-1, -1, -1, -1);
    int4 gd = make_int4(-1, -1, -1, -1);
    if (h > 0)      gu = *(const int4*)(gtb + p0 - WW);
    if (h < HH - 1) gd = *(const int4*)(gtb + p0 + WW);
    const int gl = (w > 0)       ? gtb[p0 - 1] : -1;
    const int gr = (w + 4 < WW)  ? gtb[p0 + 4] : -1;

    const int gc[4]  = {g.x, g.y, g.z, g.w};
    const int gup[4] = {gu.x, gu.y, gu.z, gu.w};
    const int gdn[4] = {gd.x, gd.y, gd.z, gd.w};
    const int glf[4] = {gl, g.x, g.y, g.z};
    const int grt[4] = {g.y, g.z, g.w, gr};

#pragma unroll
    for (int j = 0; j < 4; ++j) {
        const int k = gc[j];
        const bool eroded = (glf[j] == k) & (grt[j] == k) & (gup[j] == k) & (gdn[j] == k);
        if (k >= 1 && !eroded) {
            atomicAdd(&s_kl[k], kl[j]);
            atomicAdd(&s_n[k], 1.0f);
        }
    }
    __syncthreads();

    if (tid >= 1 && tid <= KB) {
        atomicAdd(&ws[b * KB + (tid - 1)], s_kl[tid]);
        atomicAdd(&ws[NBINS + b * KB + (tid - 1)], s_n[tid]);
    }
}

__global__ void finalize_kernel(const float* __restrict__ ws,
                                const int* __restrict__ gt,
                                float* __restrict__ out) {
    __shared__ float partial[128];
    const int tid = threadIdx.x;  // 128 threads
    float t = 0.0f;
    if (tid < NBINS) {
        const int b = tid / KB;
        const int k = (tid % KB) + 1;
        const float kl = ws[tid];
        const float n  = ws[NBINS + tid];
        // Pixel p=0 of image b is a corner -> boundary iff gt[b,0,0] >= 1.
        // valid = exists boundary pixel with flat index > 0.
        const int k0 = gt[(size_t)b * PP];
        const float sub = (k0 == k) ? 1.0f : 0.0f;   // k >= 1 always here
        const float npos = n - sub;
        t = (npos > 0.0f) ? (kl / ((float)CC * fmaxf(n, 1.0f))) : 0.0f;
    }
    partial[tid] = t;
    __syncthreads();
    for (int s = 64; s > 0; s >>= 1) {
        if (tid < s) partial[tid] += partial[tid + s];
        __syncthreads();
    }
    if (tid == 0) out[0] = partial[0];  // LOSS_WEIGHT * TAU^2 = 1
}

extern "C" void kernel_launch(void* const* d_in, const int* in_sizes, int n_in,
                              void* d_out, int out_size, void* d_ws, size_t ws_size,
                              hipStream_t stream) {
    const float* S  = (const float*)d_in[0];
    const float* T  = (const float*)d_in[1];
    const int*   gt = (const int*)d_in[2];
    float* out = (float*)d_out;
    float* ws  = (float*)d_ws;

    hipLaunchKernelGGL(zero_ws_kernel, dim3(1), dim3(256), 0, stream, ws);
    hipLaunchKernelGGL(boundary_kl_kernel, dim3(BB * BLOCKS_PER_IMG), dim3(256), 0, stream,
                       S, T, gt, ws);
    hipLaunchKernelGGL(finalize_kernel, dim3(1), dim3(128), 0, stream, ws, gt, out);
}